// Round 1
// baseline (2517.799 us; speedup 1.0000x reference)
//
#include <hip/hip_runtime.h>
#include <hip/hip_bf16.h>
#include <math.h>

#define E_DIM 768
#define T_SEQ 1024
#define B_SZ  2
#define NHEAD 12
#define HDIM  64
#define NLAY  4
#define FF_DIM 3072
#define VOCAB 50257
#define M_ROWS 2048   // B*T

typedef short bf16x8 __attribute__((ext_vector_type(8)));
typedef float floatx4 __attribute__((ext_vector_type(4)));

__device__ __forceinline__ unsigned short f2bf(float f) {
    union { __hip_bfloat16 h; unsigned short u; } cv;
    cv.h = __float2bfloat16(f);
    return cv.u;
}

// ---------------- embedding: x = tok_emb[ids] + pos_emb ----------------
__global__ __launch_bounds__(256) void embed_kernel(
    const int* __restrict__ ids, const float* __restrict__ tok,
    const float* __restrict__ pos, float* __restrict__ x)
{
    int row = blockIdx.x;                 // 0..2047 (b*T + t)
    int t = row & (T_SEQ - 1);
    int id = ids[row];
    const float* te = tok + (size_t)id * E_DIM;
    const float* pe = pos + (size_t)t * E_DIM;
    float* xr = x + (size_t)row * E_DIM;
    for (int e = threadIdx.x; e < E_DIM; e += 256) xr[e] = te[e] + pe[e];
}

// ---------------- layernorm (fp32 in, bf16 out) ----------------
__global__ __launch_bounds__(256) void ln_kernel(
    const float* __restrict__ x, const float* __restrict__ scale,
    const float* __restrict__ bias, unsigned short* __restrict__ out)
{
    int row = blockIdx.x;
    const float* xr = x + (size_t)row * E_DIM;
    int tid = threadIdx.x;
    float v0 = xr[tid], v1 = xr[tid + 256], v2 = xr[tid + 512];
    float s  = v0 + v1 + v2;
    float sq = v0 * v0 + v1 * v1 + v2 * v2;
    for (int o = 32; o; o >>= 1) {
        s  += __shfl_down(s,  o, 64);
        sq += __shfl_down(sq, o, 64);
    }
    __shared__ float red[8];
    int wid = tid >> 6;
    if ((tid & 63) == 0) { red[wid] = s; red[wid + 4] = sq; }
    __syncthreads();
    float ts = red[0] + red[1] + red[2] + red[3];
    float tq = red[4] + red[5] + red[6] + red[7];
    float mean = ts * (1.0f / E_DIM);
    float var  = tq * (1.0f / E_DIM) - mean * mean;
    float rstd = rsqrtf(var + 1e-5f);
    unsigned short* orow = out + (size_t)row * E_DIM;
    orow[tid]       = f2bf((v0 - mean) * rstd * scale[tid]       + bias[tid]);
    orow[tid + 256] = f2bf((v1 - mean) * rstd * scale[tid + 256] + bias[tid + 256]);
    orow[tid + 512] = f2bf((v2 - mean) * rstd * scale[tid + 512] + bias[tid + 512]);
}

// ---------------- GEMM: C[M,N] = A[M,K](bf16) @ W[N,K]^T(fp32) ----------------
// epilogue: +bias, exact GELU, +residual(fp32), out fp32 or bf16
__global__ __launch_bounds__(256) void gemm_bt(
    const unsigned short* __restrict__ A, const float* __restrict__ W,
    float* __restrict__ outf, unsigned short* __restrict__ outb,
    const float* __restrict__ bias, const float* __restrict__ resid,
    int K, int N, int do_gelu)
{
    __shared__ __align__(16) unsigned short As[128 * 40];
    __shared__ __align__(16) unsigned short Bs[128 * 40];
    const int tid = threadIdx.x;
    const int bm = blockIdx.y, bn = blockIdx.x;
    const int lane = tid & 63, wid = tid >> 6;
    const int quad = lane >> 4, l16 = lane & 15;
    const int wm = wid >> 1, wn = wid & 1;

    floatx4 acc[4][4];
    #pragma unroll
    for (int mt = 0; mt < 4; ++mt)
        #pragma unroll
        for (int nt = 0; nt < 4; ++nt) acc[mt][nt] = (floatx4)0.0f;

    for (int k0 = 0; k0 < K; k0 += 32) {
        __syncthreads();
        // stage A tile 128x32 (bf16 direct copy, 16B per thread x2)
        #pragma unroll
        for (int i = 0; i < 2; ++i) {
            int c = tid + i * 256;
            int r = c >> 2, c8 = (c & 3) * 8;
            *(uint4*)&As[r * 40 + c8] =
                *(const uint4*)&A[(size_t)(bm * 128 + r) * K + k0 + c8];
        }
        // stage B tile 128x32 (fp32 -> bf16 convert)
        #pragma unroll
        for (int i = 0; i < 2; ++i) {
            int c = tid + i * 256;
            int r = c >> 2, c8 = (c & 3) * 8;
            int gn = bn * 128 + r;
            float f[8];
            if (gn < N) {
                const float* src = &W[(size_t)gn * K + k0 + c8];
                float4 a0 = *(const float4*)src;
                float4 a1 = *(const float4*)(src + 4);
                f[0] = a0.x; f[1] = a0.y; f[2] = a0.z; f[3] = a0.w;
                f[4] = a1.x; f[5] = a1.y; f[6] = a1.z; f[7] = a1.w;
            } else {
                #pragma unroll
                for (int j = 0; j < 8; ++j) f[j] = 0.0f;
            }
            union { unsigned short u[8]; uint4 v; } cv;
            #pragma unroll
            for (int j = 0; j < 8; ++j) cv.u[j] = f2bf(f[j]);
            *(uint4*)&Bs[r * 40 + c8] = cv.v;
        }
        __syncthreads();

        bf16x8 af[4], bfr[4];
        #pragma unroll
        for (int mt = 0; mt < 4; ++mt)
            af[mt] = *(const bf16x8*)&As[(wm * 64 + mt * 16 + l16) * 40 + quad * 8];
        #pragma unroll
        for (int nt = 0; nt < 4; ++nt)
            bfr[nt] = *(const bf16x8*)&Bs[(wn * 64 + nt * 16 + l16) * 40 + quad * 8];
        #pragma unroll
        for (int mt = 0; mt < 4; ++mt)
            #pragma unroll
            for (int nt = 0; nt < 4; ++nt)
                acc[mt][nt] = __builtin_amdgcn_mfma_f32_16x16x32_bf16(
                    af[mt], bfr[nt], acc[mt][nt], 0, 0, 0);
    }

    // epilogue
    #pragma unroll
    for (int mt = 0; mt < 4; ++mt) {
        #pragma unroll
        for (int nt = 0; nt < 4; ++nt) {
            int col = bn * 128 + wn * 64 + nt * 16 + l16;
            if (col >= N) continue;
            float bv = bias ? bias[col] : 0.0f;
            #pragma unroll
            for (int r = 0; r < 4; ++r) {
                int row = bm * 128 + wm * 64 + mt * 16 + quad * 4 + r;
                float v = acc[mt][nt][r] + bv;
                if (do_gelu) v = 0.5f * v * (1.0f + erff(v * 0.70710678118654752f));
                size_t idx = (size_t)row * N + col;
                if (resid) v += resid[idx];
                if (outf) outf[idx] = v;
                else      outb[idx] = f2bf(v);
            }
        }
    }
}

// ---------------- flash attention: qkv(bf16) -> attno(bf16) ----------------
__global__ __launch_bounds__(256) void attn_kernel(
    const unsigned short* __restrict__ qkv, unsigned short* __restrict__ attno)
{
    __shared__ __align__(16) unsigned short Qs[64 * 88];
    __shared__ __align__(16) unsigned short Ks[64 * 88];
    __shared__ __align__(16) unsigned short Vt[64 * 88];
    __shared__ __align__(16) unsigned short Ps[4][16 * 88];

    const int tid = threadIdx.x;
    const int qtile = blockIdx.x;   // 0..15
    const int h = blockIdx.y;       // 0..11
    const int b = blockIdx.z;       // 0..1
    const int lane = tid & 63, wid = tid >> 6;
    const int quad = lane >> 4, l16 = lane & 15;

    // stage Q tile (64 rows x 64 dims)
    #pragma unroll
    for (int i = 0; i < 2; ++i) {
        int c = tid + i * 256;
        int r = c >> 3, c8 = (c & 7) * 8;
        int row = b * T_SEQ + qtile * 64 + r;
        *(uint4*)&Qs[r * 88 + c8] =
            *(const uint4*)&qkv[(size_t)row * (3 * E_DIM) + h * HDIM + c8];
    }

    float m_i[4], l_i[4];
    floatx4 acco[4];
    #pragma unroll
    for (int r = 0; r < 4; ++r) { m_i[r] = -INFINITY; l_i[r] = 0.0f; }
    #pragma unroll
    for (int dt = 0; dt < 4; ++dt) acco[dt] = (floatx4)0.0f;

    for (int kt = 0; kt <= qtile; ++kt) {
        __syncthreads();
        // stage K tile
        #pragma unroll
        for (int i = 0; i < 2; ++i) {
            int c = tid + i * 256;
            int r = c >> 3, c8 = (c & 7) * 8;
            int row = b * T_SEQ + kt * 64 + r;
            *(uint4*)&Ks[r * 88 + c8] =
                *(const uint4*)&qkv[(size_t)row * (3 * E_DIM) + E_DIM + h * HDIM + c8];
        }
        // stage V transposed: Vt[d][t]
        {
            int t = tid >> 2, d0 = (tid & 3) * 16;
            int row = b * T_SEQ + kt * 64 + t;
            const unsigned short* src =
                &qkv[(size_t)row * (3 * E_DIM) + 2 * E_DIM + h * HDIM + d0];
            unsigned short tmp[16];
            *(uint4*)&tmp[0] = *(const uint4*)src;
            *(uint4*)&tmp[8] = *(const uint4*)(src + 8);
            #pragma unroll
            for (int j = 0; j < 16; ++j) Vt[(d0 + j) * 88 + t] = tmp[j];
        }
        __syncthreads();

        // S = Q K^T  (wave handles 16 q-rows x 64 keys)
        floatx4 accs[4];
        #pragma unroll
        for (int ct = 0; ct < 4; ++ct) accs[ct] = (floatx4)0.0f;
        #pragma unroll
        for (int ct = 0; ct < 4; ++ct)
            #pragma unroll
            for (int kk = 0; kk < 64; kk += 32) {
                bf16x8 a  = *(const bf16x8*)&Qs[(wid * 16 + l16) * 88 + kk + quad * 8];
                bf16x8 bb = *(const bf16x8*)&Ks[(ct * 16 + l16) * 88 + kk + quad * 8];
                accs[ct] = __builtin_amdgcn_mfma_f32_16x16x32_bf16(a, bb, accs[ct], 0, 0, 0);
            }

        // mask + online softmax (C layout: row = quad*4+r, col = l16)
        float p[4][4];
        #pragma unroll
        for (int ct = 0; ct < 4; ++ct)
            #pragma unroll
            for (int r = 0; r < 4; ++r) {
                float s = accs[ct][r] * 0.125f;
                int kg = kt * 64 + ct * 16 + l16;
                int qg = qtile * 64 + wid * 16 + quad * 4 + r;
                p[ct][r] = (kg > qg) ? -INFINITY : s;
            }
        float alpha[4];
        #pragma unroll
        for (int r = 0; r < 4; ++r) {
            float rm = fmaxf(fmaxf(p[0][r], p[1][r]), fmaxf(p[2][r], p[3][r]));
            for (int m = 1; m < 16; m <<= 1) rm = fmaxf(rm, __shfl_xor(rm, m, 64));
            float mn = fmaxf(m_i[r], rm);
            alpha[r] = __expf(m_i[r] - mn);
            float rs = 0.0f;
            #pragma unroll
            for (int ct = 0; ct < 4; ++ct) {
                p[ct][r] = __expf(p[ct][r] - mn);
                rs += p[ct][r];
            }
            for (int m = 1; m < 16; m <<= 1) rs += __shfl_xor(rs, m, 64);
            l_i[r] = l_i[r] * alpha[r] + rs;
            m_i[r] = mn;
        }
        // write P to per-wave LDS (C layout -> A layout round trip)
        #pragma unroll
        for (int ct = 0; ct < 4; ++ct)
            #pragma unroll
            for (int r = 0; r < 4; ++r)
                Ps[wid][(quad * 4 + r) * 88 + ct * 16 + l16] = f2bf(p[ct][r]);
        // rescale O accumulator
        #pragma unroll
        for (int dt = 0; dt < 4; ++dt)
            #pragma unroll
            for (int r = 0; r < 4; ++r) acco[dt][r] *= alpha[r];
        __syncthreads();
        // O += P V
        #pragma unroll
        for (int dt = 0; dt < 4; ++dt)
            #pragma unroll
            for (int kk = 0; kk < 64; kk += 32) {
                bf16x8 a  = *(const bf16x8*)&Ps[wid][l16 * 88 + kk + quad * 8];
                bf16x8 bb = *(const bf16x8*)&Vt[(dt * 16 + l16) * 88 + kk + quad * 8];
                acco[dt] = __builtin_amdgcn_mfma_f32_16x16x32_bf16(a, bb, acco[dt], 0, 0, 0);
            }
    }

    // normalize + store
    #pragma unroll
    for (int dt = 0; dt < 4; ++dt)
        #pragma unroll
        for (int r = 0; r < 4; ++r) {
            int trow = qtile * 64 + wid * 16 + quad * 4 + r;
            float v = acco[dt][r] / l_i[r];
            attno[(size_t)(b * T_SEQ + trow) * E_DIM + h * HDIM + dt * 16 + l16] = f2bf(v);
        }
}

// ---------------- host-side orchestration ----------------
extern "C" void kernel_launch(void* const* d_in, const int* in_sizes, int n_in,
                              void* d_out, int out_size, void* d_ws, size_t ws_size,
                              hipStream_t stream)
{
    const int*   ids  = (const int*)d_in[0];
    const float* tok  = (const float*)d_in[1];
    const float* pos  = (const float*)d_in[2];
    const float* ln1s = (const float*)d_in[3];
    const float* ln1b = (const float*)d_in[4];
    const float* qkvw = (const float*)d_in[5];
    const float* outw = (const float*)d_in[6];
    const float* ln2s = (const float*)d_in[7];
    const float* ln2b = (const float*)d_in[8];
    const float* fc1w = (const float*)d_in[9];
    const float* fc1b = (const float*)d_in[10];
    const float* fc2w = (const float*)d_in[11];
    const float* fc2b = (const float*)d_in[12];
    const float* lnfs = (const float*)d_in[13];
    const float* lnfb = (const float*)d_in[14];

    char* ws = (char*)d_ws;
    float*          x     = (float*)ws;                       // 2048*768*4  = 6291456
    unsigned short* hbuf  = (unsigned short*)(ws + 6291456);  // 2048*768*2  = 3145728
    unsigned short* qkvb  = (unsigned short*)(ws + 9437184);  // 2048*2304*2 = 9437184
    unsigned short* attno = (unsigned short*)(ws + 18874368); // 2048*768*2  = 3145728
    unsigned short* ffnb  = (unsigned short*)(ws + 22020096); // 2048*3072*2 = 12582912
    // total ws usage: 34603008 bytes (~34.6 MB)

    embed_kernel<<<M_ROWS, 256, 0, stream>>>(ids, tok, pos, x);

    for (int l = 0; l < NLAY; ++l) {
        ln_kernel<<<M_ROWS, 256, 0, stream>>>(x, ln1s + l * E_DIM, ln1b + l * E_DIM, hbuf);
        gemm_bt<<<dim3(18, 16), 256, 0, stream>>>(
            hbuf, qkvw + (size_t)l * 3 * E_DIM * E_DIM, nullptr, qkvb,
            nullptr, nullptr, E_DIM, 3 * E_DIM, 0);
        attn_kernel<<<dim3(16, NHEAD, B_SZ), 256, 0, stream>>>(qkvb, attno);
        gemm_bt<<<dim3(6, 16), 256, 0, stream>>>(
            attno, outw + (size_t)l * E_DIM * E_DIM, x, nullptr,
            nullptr, x, E_DIM, E_DIM, 0);
        ln_kernel<<<M_ROWS, 256, 0, stream>>>(x, ln2s + l * E_DIM, ln2b + l * E_DIM, hbuf);
        gemm_bt<<<dim3(24, 16), 256, 0, stream>>>(
            hbuf, fc1w + (size_t)l * FF_DIM * E_DIM, nullptr, ffnb,
            fc1b + l * FF_DIM, nullptr, E_DIM, FF_DIM, 1);
        gemm_bt<<<dim3(6, 16), 256, 0, stream>>>(
            ffnb, fc2w + (size_t)l * E_DIM * FF_DIM, x, nullptr,
            fc2b + l * E_DIM, x, FF_DIM, E_DIM, 0);
    }

    ln_kernel<<<M_ROWS, 256, 0, stream>>>(x, lnfs, lnfb, hbuf);
    gemm_bt<<<dim3((VOCAB + 127) / 128, 16), 256, 0, stream>>>(
        hbuf, tok, (float*)d_out, nullptr, nullptr, nullptr, E_DIM, VOCAB, 0);
}